// Round 19
// baseline (186.562 us; speedup 1.0000x reference)
//
#include <hip/hip_runtime.h>

// B=2, C=256, H=W=64, P=3 -> Hp=Wp=62, Np=3844.
// X = A^T B via f16 MFMA hi/lo split (K=768), stored TILE-MAJOR.
// GEMM: R18 (2 barriers/kt, counted vmcnt(8) ledger, k-major pack with
// source-side XOR swizzle, swapped-operand float4 epilogue, dual-batch).
// corr (this round): S=4 diagonal chunks, 1024 threads -- stage 6 tiles
// (96 KB) via global_load_lds, FOUR parallel stencil steps (s = t>>8);
// read amplification 2.0 -> 1.5. keys get a dedicated ws slot so the
// memset runs concurrent with the gemm (was serialized via Apack alias).

typedef _Float16 half8 __attribute__((ext_vector_type(8)));
typedef float floatx4 __attribute__((ext_vector_type(4)));
typedef __attribute__((address_space(1))) const void gv_t;
typedef __attribute__((address_space(3))) void lv_t;

__device__ __forceinline__ unsigned long long pack_key(float v, unsigned int pidx) {
  unsigned int b = __float_as_uint(v);
  b = (b & 0x80000000u) ? ~b : (b | 0x80000000u);   // total order on floats
  return ((unsigned long long)b << 32) | (unsigned int)(~pidx);  // tie -> min pidx
}

// ---------------------------------------------------------------------------
// prep: SINGLE-PASS per-pixel L2 norm + f16 hi/lo split + k-major pack (R12).
__global__ void prep_kernel(const float* __restrict__ df1, const float* __restrict__ df2,
                            _Float16* __restrict__ Apack, _Float16* __restrict__ Bpack) {
  __shared__ float red[256];
  const int tid = threadIdx.x, q = tid >> 6, lane = tid & 63;
  int g = blockIdx.x * 64 + lane;           // pixel-task 0..16383
  int pix = g & 4095;
  int bm = g >> 12;
  int b = bm >> 1, m = bm & 1;              // m=0: df1 -> Bpack, m=1: df2 -> Apack
  const float* src = (m ? df2 : df1) + (size_t)b * 1048576 + pix;

  float v[64];
#pragma unroll
  for (int j = 0; j < 64; ++j) v[j] = src[(size_t)(q * 64 + j) * 4096];

  float ss = 0.f;
#pragma unroll
  for (int j = 0; j < 64; ++j) ss += v[j] * v[j];
  red[tid] = ss;
  __syncthreads();
  float tot = red[lane] + red[lane + 64] + red[lane + 128] + red[lane + 192];
  float sc = 1.f / fmaxf(sqrtf(tot), 1e-12f);

  _Float16* P = (m ? Apack : Bpack) + (size_t)b * 3145728;

#pragma unroll
  for (int j0 = 0; j0 < 64; j0 += 8) {
    half8 hi, lo;
#pragma unroll
    for (int j = 0; j < 8; ++j) {
      float x = v[j0 + j] * sc;
      _Float16 h = (_Float16)x;
      hi[j] = h;
      lo[j] = (_Float16)(4096.f * (x - (float)h));
    }
    int oj = q * 8 + (j0 >> 3);             // octet-in-segment 0..31
    _Float16* p0 = P + ((size_t)oj * 4096 + pix) * 8;          // seg 0
    _Float16* p1 = P + ((size_t)(32 + oj) * 4096 + pix) * 8;   // seg 1
    _Float16* p2 = P + ((size_t)(64 + oj) * 4096 + pix) * 8;   // seg 2
    if (m) { *(half8*)p0 = hi; *(half8*)p1 = lo; *(half8*)p2 = hi; }   // A=[hi|lo|hi]
    else   { *(half8*)p0 = lo; *(half8*)p1 = hi; *(half8*)p2 = hi; }   // B=[lo|hi|hi]
  }
}

// ---------------------------------------------------------------------------
// Dual-batch GEMM (R18): blocks [0,256) -> batch 0, [256,512) -> batch 1.
__global__ __launch_bounds__(512, 2) void gemm_mfma(const _Float16* __restrict__ A,
                                                    const _Float16* __restrict__ B,
                                                    float* __restrict__ X) {
  __shared__ _Float16 As[2][2][256][32];    // [buf][khalf][row][32 f16] = 64 KB
  __shared__ _Float16 Bs[2][2][256][32];    // 64 KB

  const int batch = blockIdx.x >> 8;
  int bid = blockIdx.x & 255;               // XCD swizzle within each batch
  int swb = (bid & 7) * 32 + (bid >> 3);
  int bx = swb & 15, by = swb >> 4;
  const int u0 = by << 8, v0 = bx << 8;

  const int tid = threadIdx.x, lane = tid & 63, wid = tid >> 6;
  const int wr = wid >> 2, wc = wid & 3;    // 2 x 4 waves; per-wave out 128x64
  const int frow = lane & 15, fhi = lane >> 4;
  const int fsw = (lane >> 1) & 3;
  const int fslot = (fhi ^ fsw) * 8;

  floatx4 acc[8][4];
#pragma unroll
  for (int i = 0; i < 8; ++i)
#pragma unroll
    for (int j = 0; j < 4; ++j) acc[i][j] = (floatx4){0.f, 0.f, 0.f, 0.f};

  // k-major pack: element addr = (o*4096 + pixel)*8 ; pixel = u0|v0 + row
  const _Float16* Abase = A + (size_t)batch * 3145728 + (size_t)u0 * 8;
  const _Float16* Bbase = B + (size_t)batch * 3145728 + (size_t)v0 * 8;
  float* Xb = X + (size_t)batch * 16777216;

  // STG: LDS[buf][kh][row][s] <- global octet (kt*8 + kh*4 + (s ^ ((row>>1)&3)))
#define STG(OPB, LDSB, kt, kh)                                                \
  {                                                                           \
    _Pragma("unroll") for (int i_ = 0; i_ < 2; ++i_) {                        \
      int c_ = i_ * 512 + tid;                                                \
      int r_ = c_ >> 2, s_ = c_ & 3;                                          \
      int o_ = (kt) * 8 + (kh) * 4 + (s_ ^ ((r_ >> 1) & 3));                  \
      __builtin_amdgcn_global_load_lds(                                       \
          (gv_t*)(OPB + ((size_t)o_ * 4096 + r_) * 8),                        \
          (lv_t*)(&LDSB[(kt) & 1][kh][0][0] + c_ * 8), 16, 0, 0);             \
    }                                                                         \
  }

  // prologue: kh0(0), kh1(0), kh0(1) staged
  STG(Abase, As, 0, 0); STG(Bbase, Bs, 0, 0);
  STG(Abase, As, 0, 1); STG(Bbase, Bs, 0, 1);
  STG(Abase, As, 1, 0); STG(Bbase, Bs, 1, 0);
  asm volatile("s_waitcnt vmcnt(8)" ::: "memory");    // kh0(0) A,B landed
  __builtin_amdgcn_sched_barrier(0);
  __builtin_amdgcn_s_barrier();

  for (int kt = 0; kt < 12; ++kt) {
    const int buf = kt & 1;
    const _Float16* LA0 = &As[buf][0][0][0];
    const _Float16* LB0 = &Bs[buf][0][0][0];
    const _Float16* LA1 = &As[buf][1][0][0];
    const _Float16* LB1 = &Bs[buf][1][0][0];
    half8 bf[4], af0[4], af1[4];

    // ========== Phase A: kh0 -> 32 MFMA (one barrier at end) ==========
#pragma unroll
    for (int g = 0; g < 4; ++g)
      bf[g] = *(const half8*)(LB0 + (wc * 64 + g * 16 + frow) * 32 + fslot);
#pragma unroll
    for (int f = 0; f < 4; ++f)
      af0[f] = *(const half8*)(LA0 + (wr * 128 + f * 16 + frow) * 32 + fslot);
#pragma unroll
    for (int f = 0; f < 4; ++f)
      af1[f] = *(const half8*)(LA0 + (wr * 128 + 64 + f * 16 + frow) * 32 + fslot);
    if (kt <= 10) { STG(Abase, As, kt + 1, 1); STG(Bbase, Bs, kt + 1, 1); }
    __builtin_amdgcn_sched_barrier(0);
    asm volatile("s_waitcnt lgkmcnt(0)" ::: "memory");   // frags in regs
    __builtin_amdgcn_sched_barrier(0);
    __builtin_amdgcn_s_setprio(1);
#pragma unroll
    for (int f = 0; f < 4; ++f)
#pragma unroll
      for (int g = 0; g < 4; ++g)
        acc[f][g] = __builtin_amdgcn_mfma_f32_16x16x32_f16(bf[g], af0[f], acc[f][g], 0, 0, 0);
#pragma unroll
    for (int f = 0; f < 4; ++f)
#pragma unroll
      for (int g = 0; g < 4; ++g)
        acc[4 + f][g] = __builtin_amdgcn_mfma_f32_16x16x32_f16(bf[g], af1[f], acc[4 + f][g], 0, 0, 0);
    __builtin_amdgcn_s_setprio(0);
    __builtin_amdgcn_sched_barrier(0);
    if (kt <= 10) asm volatile("s_waitcnt vmcnt(8)" ::: "memory");  // kh1(kt) landed
    else          asm volatile("s_waitcnt vmcnt(0)" ::: "memory");
    __builtin_amdgcn_sched_barrier(0);
    __builtin_amdgcn_s_barrier();           // kh1(kt) visible to all waves

    // ========== Phase B: kh1 -> 32 MFMA (one barrier at end) ==========
#pragma unroll
    for (int g = 0; g < 4; ++g)
      bf[g] = *(const half8*)(LB1 + (wc * 64 + g * 16 + frow) * 32 + fslot);
#pragma unroll
    for (int f = 0; f < 4; ++f)
      af0[f] = *(const half8*)(LA1 + (wr * 128 + f * 16 + frow) * 32 + fslot);
#pragma unroll
    for (int f = 0; f < 4; ++f)
      af1[f] = *(const half8*)(LA1 + (wr * 128 + 64 + f * 16 + frow) * 32 + fslot);
    if (kt <= 9) { STG(Abase, As, kt + 2, 0); STG(Bbase, Bs, kt + 2, 0); }
    __builtin_amdgcn_sched_barrier(0);
    asm volatile("s_waitcnt lgkmcnt(0)" ::: "memory");
    __builtin_amdgcn_sched_barrier(0);
    __builtin_amdgcn_s_setprio(1);
#pragma unroll
    for (int f = 0; f < 4; ++f)
#pragma unroll
      for (int g = 0; g < 4; ++g)
        acc[f][g] = __builtin_amdgcn_mfma_f32_16x16x32_f16(bf[g], af0[f], acc[f][g], 0, 0, 0);
#pragma unroll
    for (int f = 0; f < 4; ++f)
#pragma unroll
      for (int g = 0; g < 4; ++g)
        acc[4 + f][g] = __builtin_amdgcn_mfma_f32_16x16x32_f16(bf[g], af1[f], acc[4 + f][g], 0, 0, 0);
    __builtin_amdgcn_s_setprio(0);
    __builtin_amdgcn_sched_barrier(0);
    if (kt == 7) {  // cross terms (K<512: kt 0..7) done -> scale by 2^-12
#pragma unroll
      for (int i = 0; i < 8; ++i)
#pragma unroll
        for (int j = 0; j < 4; ++j)
#pragma unroll
          for (int r = 0; r < 4; ++r) acc[i][j][r] *= 0.000244140625f;
    }
    if (kt <= 9)       asm volatile("s_waitcnt vmcnt(8)" ::: "memory");  // kh0(kt+1)
    else if (kt == 10) asm volatile("s_waitcnt vmcnt(4)" ::: "memory");
    __builtin_amdgcn_sched_barrier(0);
    __builtin_amdgcn_s_barrier();           // kh0(kt+1) visible; buf readers done
  }
#undef STG

  // epilogue: swapped-operand C/D layout -> float4 stores (verified R9-R18).
#pragma unroll
  for (int f = 0; f < 8; ++f) {
    int u = u0 + wr * 128 + f * 16 + frow;
    int a4 = u >> 6, ub = u & 63;
#pragma unroll
    for (int g = 0; g < 4; ++g) {
      int v = v0 + wc * 64 + g * 16 + fhi * 4;
      int c4 = v >> 6, vb = v & 63;
      float* p = Xb + ((size_t)(a4 * 64 + c4) << 12) + (ub << 6) + vb;
      *(float4*)p = (float4){acc[f][g][0], acc[f][g][1], acc[f][g][2], acc[f][g][3]};
    }
  }
}

// ---------------------------------------------------------------------------
// corr_diag4p: block (ch, di, z), 1024 threads. Stages cnt+2 (<=6) diagonal
// tiles via global_load_lds (96 KB); quarter s = t>>8 computes stencil step s
// (four steps in parallel); per-quarter 16-group LDS merge; atomicMax argmax.
__global__ __launch_bounds__(1024) void corr_diag4p(const float* __restrict__ X,
                                                    unsigned long long* __restrict__ key,
                                                    long xstride) {
  __shared__ float T[6][4096];      // 96 KB
  __shared__ float mv[4][16][64];   // 16 KB (follows T: stencil overread lands here, masked)
  __shared__ int mi[4][16][64];     // 16 KB
  const int ch = blockIdx.x;                // 0..15
  const int di = blockIdx.y;                // 0..122
  const int z = blockIdx.z;
  const int d = di - 61;
  const int ad = d < 0 ? -d : d;
  const int L = 62 - ad;
  const int s0 = ch * 4;
  if (s0 >= L) return;                      // block-uniform exit
  const int cnt = (L - s0) < 4 ? (L - s0) : 4;
  const int p_lo = d < 0 ? -d : 0;
  const int pi0 = p_lo + s0, qi0 = pi0 + d;
  const int t = threadIdx.x;
  const float* Xz = X + (size_t)z * xstride;
  unsigned long long* kz = key + (size_t)z * 3844;

  // stage cnt+2 tiles: per tile 1 gload_lds/thread (16B), linear dest
  for (int j = 0; j < cnt + 2; ++j) {
    const float* src = Xz + ((size_t)((pi0 + j) * 64 + (qi0 + j)) << 12);
    __builtin_amdgcn_global_load_lds((gv_t*)(src + t * 4),
                                     (lv_t*)(&T[j][0] + t * 4), 16, 0, 0);
  }
  __syncthreads();                          // drains vmcnt -> tiles visible

  const int s = t >> 8;                     // step owned by this quarter (0..3)
  const int tt = t & 255;
  const int pg = tt >> 4, qg = tt & 15;
  const int pj0 = pg * 4, qj0 = qg * 4;
  const bool active = s < cnt;              // inactive quarter: garbage, masked

  const float* T0 = T[s];
  const float* T1 = T[s + 1];
  const float* T2 = T[s + 2];
  float v[6][8];
#pragma unroll
  for (int r = 0; r < 6; ++r) {
    int rr = pj0 + r; if (rr > 63) rr = 63;   // clamped rows feed only invalid pj
    int e = rr * 64 + qj0;
    float4 a0 = *(const float4*)&T0[e],     a1 = *(const float4*)&T1[e],     a2 = *(const float4*)&T2[e];
    float4 b0 = *(const float4*)&T0[e + 4], b1 = *(const float4*)&T1[e + 4], b2 = *(const float4*)&T2[e + 4];
    v[r][0] = a0.x + a1.x + a2.x; v[r][1] = a0.y + a1.y + a2.y;
    v[r][2] = a0.z + a1.z + a2.z; v[r][3] = a0.w + a1.w + a2.w;
    v[r][4] = b0.x + b1.x + b2.x; v[r][5] = b0.y + b1.y + b2.y;
    v[r][6] = b0.z + b1.z + b2.z; v[r][7] = b0.w + b1.w + b2.w;
  }
  float acc[4][4];
#pragma unroll
  for (int i = 0; i < 4; ++i)
#pragma unroll
    for (int j = 0; j < 4; ++j)
      acc[i][j] = v[i][j] + v[i + 1][j + 1] + v[i + 2][j + 2];

  float bv[4]; int bp[4];
#pragma unroll
  for (int j = 0; j < 4; ++j) { bv[j] = -3.0e38f; bp[j] = 0; }
#pragma unroll
  for (int i = 0; i < 4; ++i) {
    bool pvalid = (pj0 + i) < 62;
#pragma unroll
    for (int j = 0; j < 4; ++j) {
      float val = pvalid ? acc[i][j] : -3.0e38f;
      if (val > bv[j]) { bv[j] = val; bp[j] = pj0 + i; }   // ascending pj, strict >
    }
  }
#pragma unroll
  for (int j = 0; j < 4; ++j) { mv[s][pg][qj0 + j] = bv[j]; mi[s][pg][qj0 + j] = bp[j]; }
  __syncthreads();

  if (active && tt < 62) {
    float best = -3.0e38f; int bpj = 0;
    for (int g = 0; g < 16; ++g) {           // ascending g = ascending pj
      float vv = mv[s][g][tt];
      if (vv > best) { best = vv; bpj = mi[s][g][tt]; }
    }
    const int pi = pi0 + s, qi = qi0 + s;
    atomicMax(&kz[qi * 62 + tt], pack_key(best, (unsigned)(pi * 62 + bpj)));
  }
}

// ---------------------------------------------------------------------------
__global__ void flow_kernel(const unsigned long long* __restrict__ key,
                            float* __restrict__ out) {
  int t = blockIdx.x * 256 + threadIdx.x;
  if (t >= 147456) return;
  int comp = t & 1;
  int w = (t >> 1) & 63;
  int h = (t >> 7) & 63;
  int s = (t >> 13) % 9;
  int b = t / 73728;
  int i = s / 3, j = s % 3;
  int y = h - i, x = w - j;
  float val = 0.f;
  if (y >= 0 && x >= 0 && y < 62 && x < 62) {
    unsigned long long k = key[b * 3844 + y * 62 + x];
    int idx = (int)(~(unsigned int)k);       // low 32 bits = ~pidx
    val = (comp == 0) ? (float)(idx % 62) - (float)x : (float)(idx / 62) - (float)y;
  }
  out[t] = val;
}

// ---------------------------------------------------------------------------
extern "C" void kernel_launch(void* const* d_in, const int* in_sizes, int n_in,
                              void* d_out, int out_size, void* d_ws, size_t ws_size,
                              hipStream_t stream) {
  const float* df1 = (const float*)d_in[0];  // input  -> B operand (columns v)
  const float* df2 = (const float*)d_in[1];  // ref    -> A operand (rows u)
  float* out = (float*)d_out;

  char* ws = (char*)d_ws;
  _Float16* Apack = (_Float16*)ws;                       // 2 x 3145728 f16
  _Float16* Bpack = (_Float16*)(ws + 12582912);
  float* X = (float*)(ws + 25165824);                    // 2 x 64 MiB (dual)

  prep_kernel<<<256, 256, 0, stream>>>(df1, df2, Apack, Bpack);

  const size_t DUAL_NEED = 25165824ull + 2ull * 67108864ull + 65536ull;
  if (ws_size >= DUAL_NEED) {
    // keys in a dedicated slot AFTER the X buffers -> memset can run
    // concurrent with the gemm (no Apack alias serialization).
    unsigned long long* keys = (unsigned long long*)(ws + 25165824 + 134217728);
    hipMemsetAsync(keys, 0, 7688 * sizeof(unsigned long long), stream);
    gemm_mfma<<<512, 512, 0, stream>>>(Apack, Bpack, X);
    corr_diag4p<<<dim3(16, 123, 2), 1024, 0, stream>>>(X, keys, 16777216);
    flow_kernel<<<576, 256, 0, stream>>>(keys, out);
  } else {
    // fallback: per-batch sequential (single X buffer); keys in spare ws
    unsigned long long* keys = (unsigned long long*)(ws + 25165824 + 67108864);
    hipMemsetAsync(keys, 0, 7688 * sizeof(unsigned long long), stream);
    gemm_mfma<<<256, 512, 0, stream>>>(Apack, Bpack, X);
    corr_diag4p<<<dim3(16, 123, 1), 1024, 0, stream>>>(X, keys, 0);
    gemm_mfma<<<256, 512, 0, stream>>>(Apack + 3145728, Bpack + 3145728, X);
    corr_diag4p<<<dim3(16, 123, 1), 1024, 0, stream>>>(X, keys + 3844, 0);
    flow_kernel<<<576, 256, 0, stream>>>(keys, out);
  }
}

// Round 20
// 137.531 us; speedup vs baseline: 1.3565x; 1.3565x over previous
//
#include <hip/hip_runtime.h>

// B=2, C=256, H=W=64, P=3 -> Hp=Wp=62, Np=3844.
// X = A^T B via f16 MFMA hi/lo split (K=768), stored TILE-MAJOR.
// GEMM: R18 (2 barriers/kt, counted vmcnt(8) ledger, k-major pack with
// source-side XOR swizzle, swapped-operand float4 epilogue, dual-batch).
// corr: R17 corr_diag2p (512 thr, S=2, 80 KB LDS -> 2 blocks/CU; proven).
// R19's S=4/1024-thr corr regressed 3.4x (1 block/CU -> latency exposed);
// reverted. Kept from R19: keys in a dedicated ws slot after X so the
// memset overlaps the gemm on the stream.

typedef _Float16 half8 __attribute__((ext_vector_type(8)));
typedef float floatx4 __attribute__((ext_vector_type(4)));
typedef __attribute__((address_space(1))) const void gv_t;
typedef __attribute__((address_space(3))) void lv_t;

__device__ __forceinline__ unsigned long long pack_key(float v, unsigned int pidx) {
  unsigned int b = __float_as_uint(v);
  b = (b & 0x80000000u) ? ~b : (b | 0x80000000u);   // total order on floats
  return ((unsigned long long)b << 32) | (unsigned int)(~pidx);  // tie -> min pidx
}

// ---------------------------------------------------------------------------
// prep: SINGLE-PASS per-pixel L2 norm + f16 hi/lo split + k-major pack (R12).
__global__ void prep_kernel(const float* __restrict__ df1, const float* __restrict__ df2,
                            _Float16* __restrict__ Apack, _Float16* __restrict__ Bpack) {
  __shared__ float red[256];
  const int tid = threadIdx.x, q = tid >> 6, lane = tid & 63;
  int g = blockIdx.x * 64 + lane;           // pixel-task 0..16383
  int pix = g & 4095;
  int bm = g >> 12;
  int b = bm >> 1, m = bm & 1;              // m=0: df1 -> Bpack, m=1: df2 -> Apack
  const float* src = (m ? df2 : df1) + (size_t)b * 1048576 + pix;

  float v[64];
#pragma unroll
  for (int j = 0; j < 64; ++j) v[j] = src[(size_t)(q * 64 + j) * 4096];

  float ss = 0.f;
#pragma unroll
  for (int j = 0; j < 64; ++j) ss += v[j] * v[j];
  red[tid] = ss;
  __syncthreads();
  float tot = red[lane] + red[lane + 64] + red[lane + 128] + red[lane + 192];
  float sc = 1.f / fmaxf(sqrtf(tot), 1e-12f);

  _Float16* P = (m ? Apack : Bpack) + (size_t)b * 3145728;

#pragma unroll
  for (int j0 = 0; j0 < 64; j0 += 8) {
    half8 hi, lo;
#pragma unroll
    for (int j = 0; j < 8; ++j) {
      float x = v[j0 + j] * sc;
      _Float16 h = (_Float16)x;
      hi[j] = h;
      lo[j] = (_Float16)(4096.f * (x - (float)h));
    }
    int oj = q * 8 + (j0 >> 3);             // octet-in-segment 0..31
    _Float16* p0 = P + ((size_t)oj * 4096 + pix) * 8;          // seg 0
    _Float16* p1 = P + ((size_t)(32 + oj) * 4096 + pix) * 8;   // seg 1
    _Float16* p2 = P + ((size_t)(64 + oj) * 4096 + pix) * 8;   // seg 2
    if (m) { *(half8*)p0 = hi; *(half8*)p1 = lo; *(half8*)p2 = hi; }   // A=[hi|lo|hi]
    else   { *(half8*)p0 = lo; *(half8*)p1 = hi; *(half8*)p2 = hi; }   // B=[lo|hi|hi]
  }
}

// ---------------------------------------------------------------------------
// Dual-batch GEMM (R18): blocks [0,256) -> batch 0, [256,512) -> batch 1.
__global__ __launch_bounds__(512, 2) void gemm_mfma(const _Float16* __restrict__ A,
                                                    const _Float16* __restrict__ B,
                                                    float* __restrict__ X) {
  __shared__ _Float16 As[2][2][256][32];    // [buf][khalf][row][32 f16] = 64 KB
  __shared__ _Float16 Bs[2][2][256][32];    // 64 KB

  const int batch = blockIdx.x >> 8;
  int bid = blockIdx.x & 255;               // XCD swizzle within each batch
  int swb = (bid & 7) * 32 + (bid >> 3);
  int bx = swb & 15, by = swb >> 4;
  const int u0 = by << 8, v0 = bx << 8;

  const int tid = threadIdx.x, lane = tid & 63, wid = tid >> 6;
  const int wr = wid >> 2, wc = wid & 3;    // 2 x 4 waves; per-wave out 128x64
  const int frow = lane & 15, fhi = lane >> 4;
  const int fsw = (lane >> 1) & 3;
  const int fslot = (fhi ^ fsw) * 8;

  floatx4 acc[8][4];
#pragma unroll
  for (int i = 0; i < 8; ++i)
#pragma unroll
    for (int j = 0; j < 4; ++j) acc[i][j] = (floatx4){0.f, 0.f, 0.f, 0.f};

  // k-major pack: element addr = (o*4096 + pixel)*8 ; pixel = u0|v0 + row
  const _Float16* Abase = A + (size_t)batch * 3145728 + (size_t)u0 * 8;
  const _Float16* Bbase = B + (size_t)batch * 3145728 + (size_t)v0 * 8;
  float* Xb = X + (size_t)batch * 16777216;

  // STG: LDS[buf][kh][row][s] <- global octet (kt*8 + kh*4 + (s ^ ((row>>1)&3)))
#define STG(OPB, LDSB, kt, kh)                                                \
  {                                                                           \
    _Pragma("unroll") for (int i_ = 0; i_ < 2; ++i_) {                        \
      int c_ = i_ * 512 + tid;                                                \
      int r_ = c_ >> 2, s_ = c_ & 3;                                          \
      int o_ = (kt) * 8 + (kh) * 4 + (s_ ^ ((r_ >> 1) & 3));                  \
      __builtin_amdgcn_global_load_lds(                                       \
          (gv_t*)(OPB + ((size_t)o_ * 4096 + r_) * 8),                        \
          (lv_t*)(&LDSB[(kt) & 1][kh][0][0] + c_ * 8), 16, 0, 0);             \
    }                                                                         \
  }

  // prologue: kh0(0), kh1(0), kh0(1) staged
  STG(Abase, As, 0, 0); STG(Bbase, Bs, 0, 0);
  STG(Abase, As, 0, 1); STG(Bbase, Bs, 0, 1);
  STG(Abase, As, 1, 0); STG(Bbase, Bs, 1, 0);
  asm volatile("s_waitcnt vmcnt(8)" ::: "memory");    // kh0(0) A,B landed
  __builtin_amdgcn_sched_barrier(0);
  __builtin_amdgcn_s_barrier();

  for (int kt = 0; kt < 12; ++kt) {
    const int buf = kt & 1;
    const _Float16* LA0 = &As[buf][0][0][0];
    const _Float16* LB0 = &Bs[buf][0][0][0];
    const _Float16* LA1 = &As[buf][1][0][0];
    const _Float16* LB1 = &Bs[buf][1][0][0];
    half8 bf[4], af0[4], af1[4];

    // ========== Phase A: kh0 -> 32 MFMA (one barrier at end) ==========
#pragma unroll
    for (int g = 0; g < 4; ++g)
      bf[g] = *(const half8*)(LB0 + (wc * 64 + g * 16 + frow) * 32 + fslot);
#pragma unroll
    for (int f = 0; f < 4; ++f)
      af0[f] = *(const half8*)(LA0 + (wr * 128 + f * 16 + frow) * 32 + fslot);
#pragma unroll
    for (int f = 0; f < 4; ++f)
      af1[f] = *(const half8*)(LA0 + (wr * 128 + 64 + f * 16 + frow) * 32 + fslot);
    if (kt <= 10) { STG(Abase, As, kt + 1, 1); STG(Bbase, Bs, kt + 1, 1); }
    __builtin_amdgcn_sched_barrier(0);
    asm volatile("s_waitcnt lgkmcnt(0)" ::: "memory");   // frags in regs
    __builtin_amdgcn_sched_barrier(0);
    __builtin_amdgcn_s_setprio(1);
#pragma unroll
    for (int f = 0; f < 4; ++f)
#pragma unroll
      for (int g = 0; g < 4; ++g)
        acc[f][g] = __builtin_amdgcn_mfma_f32_16x16x32_f16(bf[g], af0[f], acc[f][g], 0, 0, 0);
#pragma unroll
    for (int f = 0; f < 4; ++f)
#pragma unroll
      for (int g = 0; g < 4; ++g)
        acc[4 + f][g] = __builtin_amdgcn_mfma_f32_16x16x32_f16(bf[g], af1[f], acc[4 + f][g], 0, 0, 0);
    __builtin_amdgcn_s_setprio(0);
    __builtin_amdgcn_sched_barrier(0);
    if (kt <= 10) asm volatile("s_waitcnt vmcnt(8)" ::: "memory");  // kh1(kt) landed
    else          asm volatile("s_waitcnt vmcnt(0)" ::: "memory");
    __builtin_amdgcn_sched_barrier(0);
    __builtin_amdgcn_s_barrier();           // kh1(kt) visible to all waves

    // ========== Phase B: kh1 -> 32 MFMA (one barrier at end) ==========
#pragma unroll
    for (int g = 0; g < 4; ++g)
      bf[g] = *(const half8*)(LB1 + (wc * 64 + g * 16 + frow) * 32 + fslot);
#pragma unroll
    for (int f = 0; f < 4; ++f)
      af0[f] = *(const half8*)(LA1 + (wr * 128 + f * 16 + frow) * 32 + fslot);
#pragma unroll
    for (int f = 0; f < 4; ++f)
      af1[f] = *(const half8*)(LA1 + (wr * 128 + 64 + f * 16 + frow) * 32 + fslot);
    if (kt <= 9) { STG(Abase, As, kt + 2, 0); STG(Bbase, Bs, kt + 2, 0); }
    __builtin_amdgcn_sched_barrier(0);
    asm volatile("s_waitcnt lgkmcnt(0)" ::: "memory");
    __builtin_amdgcn_sched_barrier(0);
    __builtin_amdgcn_s_setprio(1);
#pragma unroll
    for (int f = 0; f < 4; ++f)
#pragma unroll
      for (int g = 0; g < 4; ++g)
        acc[f][g] = __builtin_amdgcn_mfma_f32_16x16x32_f16(bf[g], af0[f], acc[f][g], 0, 0, 0);
#pragma unroll
    for (int f = 0; f < 4; ++f)
#pragma unroll
      for (int g = 0; g < 4; ++g)
        acc[4 + f][g] = __builtin_amdgcn_mfma_f32_16x16x32_f16(bf[g], af1[f], acc[4 + f][g], 0, 0, 0);
    __builtin_amdgcn_s_setprio(0);
    __builtin_amdgcn_sched_barrier(0);
    if (kt == 7) {  // cross terms (K<512: kt 0..7) done -> scale by 2^-12
#pragma unroll
      for (int i = 0; i < 8; ++i)
#pragma unroll
        for (int j = 0; j < 4; ++j)
#pragma unroll
          for (int r = 0; r < 4; ++r) acc[i][j][r] *= 0.000244140625f;
    }
    if (kt <= 9)       asm volatile("s_waitcnt vmcnt(8)" ::: "memory");  // kh0(kt+1)
    else if (kt == 10) asm volatile("s_waitcnt vmcnt(4)" ::: "memory");
    __builtin_amdgcn_sched_barrier(0);
    __builtin_amdgcn_s_barrier();           // kh0(kt+1) visible; buf readers done
  }
#undef STG

  // epilogue: swapped-operand C/D layout -> float4 stores (verified R9-R19).
#pragma unroll
  for (int f = 0; f < 8; ++f) {
    int u = u0 + wr * 128 + f * 16 + frow;
    int a4 = u >> 6, ub = u & 63;
#pragma unroll
    for (int g = 0; g < 4; ++g) {
      int v = v0 + wc * 64 + g * 16 + fhi * 4;
      int c4 = v >> 6, vb = v & 63;
      float* p = Xb + ((size_t)(a4 * 64 + c4) << 12) + (ub << 6) + vb;
      *(float4*)p = (float4){acc[f][g][0], acc[f][g][1], acc[f][g][2], acc[f][g][3]};
    }
  }
}

// ---------------------------------------------------------------------------
// corr_diag2p (R17, proven): block (ch, di, z), 512 threads. Stages cnt+2
// (<=4) diagonal tiles via global_load_lds; half s = t>>8 computes stencil
// step s (both steps in parallel); per-half 16-group LDS merge; atomicMax.
__global__ __launch_bounds__(512) void corr_diag2p(const float* __restrict__ X,
                                                   unsigned long long* __restrict__ key,
                                                   long xstride) {
  __shared__ float T[4][4096];      // 64 KB
  __shared__ float mv[2][16][64];   // 8 KB (follows T: stencil overread lands here, masked)
  __shared__ int mi[2][16][64];     // 8 KB
  const int ch = blockIdx.x;                // 0..30
  const int di = blockIdx.y;                // 0..122
  const int z = blockIdx.z;
  const int d = di - 61;
  const int ad = d < 0 ? -d : d;
  const int L = 62 - ad;
  const int s0 = ch * 2;
  if (s0 >= L) return;                      // block-uniform exit
  const int cnt = (L - s0) < 2 ? (L - s0) : 2;
  const int p_lo = d < 0 ? -d : 0;
  const int pi0 = p_lo + s0, qi0 = pi0 + d;
  const int t = threadIdx.x;
  const float* Xz = X + (size_t)z * xstride;
  unsigned long long* kz = key + (size_t)z * 3844;

  // stage cnt+2 tiles: per tile 2 gload_lds/thread (16B each), linear dest
  for (int j = 0; j < cnt + 2; ++j) {
    const float* src = Xz + ((size_t)((pi0 + j) * 64 + (qi0 + j)) << 12);
#pragma unroll
    for (int k = 0; k < 2; ++k) {
      int c = k * 512 + t;                  // float4 index 0..1023
      __builtin_amdgcn_global_load_lds((gv_t*)(src + c * 4),
                                       (lv_t*)(&T[j][0] + c * 4), 16, 0, 0);
    }
  }
  __syncthreads();                          // drains vmcnt -> tiles visible

  const int s = t >> 8;                     // step owned by this half (0/1)
  const int tt = t & 255;
  const int pg = tt >> 4, qg = tt & 15;
  const int pj0 = pg * 4, qj0 = qg * 4;
  const bool active = s < cnt;              // inactive half: garbage, masked

  const float* T0 = T[s];
  const float* T1 = T[s + 1];
  const float* T2 = T[s + 2];
  float v[6][8];
#pragma unroll
  for (int r = 0; r < 6; ++r) {
    int rr = pj0 + r; if (rr > 63) rr = 63;   // clamped rows feed only invalid pj
    int e = rr * 64 + qj0;
    float4 a0 = *(const float4*)&T0[e],     a1 = *(const float4*)&T1[e],     a2 = *(const float4*)&T2[e];
    float4 b0 = *(const float4*)&T0[e + 4], b1 = *(const float4*)&T1[e + 4], b2 = *(const float4*)&T2[e + 4];
    v[r][0] = a0.x + a1.x + a2.x; v[r][1] = a0.y + a1.y + a2.y;
    v[r][2] = a0.z + a1.z + a2.z; v[r][3] = a0.w + a1.w + a2.w;
    v[r][4] = b0.x + b1.x + b2.x; v[r][5] = b0.y + b1.y + b2.y;
    v[r][6] = b0.z + b1.z + b2.z; v[r][7] = b0.w + b1.w + b2.w;
  }
  float acc[4][4];
#pragma unroll
  for (int i = 0; i < 4; ++i)
#pragma unroll
    for (int j = 0; j < 4; ++j)
      acc[i][j] = v[i][j] + v[i + 1][j + 1] + v[i + 2][j + 2];

  float bv[4]; int bp[4];
#pragma unroll
  for (int j = 0; j < 4; ++j) { bv[j] = -3.0e38f; bp[j] = 0; }
#pragma unroll
  for (int i = 0; i < 4; ++i) {
    bool pvalid = (pj0 + i) < 62;
#pragma unroll
    for (int j = 0; j < 4; ++j) {
      float val = pvalid ? acc[i][j] : -3.0e38f;
      if (val > bv[j]) { bv[j] = val; bp[j] = pj0 + i; }   // ascending pj, strict >
    }
  }
#pragma unroll
  for (int j = 0; j < 4; ++j) { mv[s][pg][qj0 + j] = bv[j]; mi[s][pg][qj0 + j] = bp[j]; }
  __syncthreads();

  if (active && tt < 62) {
    float best = -3.0e38f; int bpj = 0;
    for (int g = 0; g < 16; ++g) {           // ascending g = ascending pj
      float vv = mv[s][g][tt];
      if (vv > best) { best = vv; bpj = mi[s][g][tt]; }
    }
    const int pi = pi0 + s, qi = qi0 + s;
    atomicMax(&kz[qi * 62 + tt], pack_key(best, (unsigned)(pi * 62 + bpj)));
  }
}

// ---------------------------------------------------------------------------
__global__ void flow_kernel(const unsigned long long* __restrict__ key,
                            float* __restrict__ out) {
  int t = blockIdx.x * 256 + threadIdx.x;
  if (t >= 147456) return;
  int comp = t & 1;
  int w = (t >> 1) & 63;
  int h = (t >> 7) & 63;
  int s = (t >> 13) % 9;
  int b = t / 73728;
  int i = s / 3, j = s % 3;
  int y = h - i, x = w - j;
  float val = 0.f;
  if (y >= 0 && x >= 0 && y < 62 && x < 62) {
    unsigned long long k = key[b * 3844 + y * 62 + x];
    int idx = (int)(~(unsigned int)k);       // low 32 bits = ~pidx
    val = (comp == 0) ? (float)(idx % 62) - (float)x : (float)(idx / 62) - (float)y;
  }
  out[t] = val;
}

// ---------------------------------------------------------------------------
extern "C" void kernel_launch(void* const* d_in, const int* in_sizes, int n_in,
                              void* d_out, int out_size, void* d_ws, size_t ws_size,
                              hipStream_t stream) {
  const float* df1 = (const float*)d_in[0];  // input  -> B operand (columns v)
  const float* df2 = (const float*)d_in[1];  // ref    -> A operand (rows u)
  float* out = (float*)d_out;

  char* ws = (char*)d_ws;
  _Float16* Apack = (_Float16*)ws;                       // 2 x 3145728 f16
  _Float16* Bpack = (_Float16*)(ws + 12582912);
  float* X = (float*)(ws + 25165824);                    // 2 x 64 MiB (dual)

  prep_kernel<<<256, 256, 0, stream>>>(df1, df2, Apack, Bpack);

  const size_t DUAL_NEED = 25165824ull + 2ull * 67108864ull + 65536ull;
  if (ws_size >= DUAL_NEED) {
    // keys in a dedicated slot AFTER the X buffers -> memset runs
    // concurrent with the gemm (no Apack alias serialization).
    unsigned long long* keys = (unsigned long long*)(ws + 25165824 + 134217728);
    hipMemsetAsync(keys, 0, 7688 * sizeof(unsigned long long), stream);
    gemm_mfma<<<512, 512, 0, stream>>>(Apack, Bpack, X);
    corr_diag2p<<<dim3(31, 123, 2), 512, 0, stream>>>(X, keys, 16777216);
    flow_kernel<<<576, 256, 0, stream>>>(keys, out);
  } else {
    // fallback: per-batch sequential (single X buffer); keys in spare ws
    unsigned long long* keys = (unsigned long long*)(ws + 25165824 + 67108864);
    hipMemsetAsync(keys, 0, 7688 * sizeof(unsigned long long), stream);
    gemm_mfma<<<256, 512, 0, stream>>>(Apack, Bpack, X);
    corr_diag2p<<<dim3(31, 123, 1), 512, 0, stream>>>(X, keys, 0);
    gemm_mfma<<<256, 512, 0, stream>>>(Apack + 3145728, Bpack + 3145728, X);
    corr_diag2p<<<dim3(31, 123, 1), 512, 0, stream>>>(X, keys + 3844, 0);
    flow_kernel<<<576, 256, 0, stream>>>(keys, out);
  }
}